// Round 1
// baseline (150.811 us; speedup 1.0000x reference)
//
#include <hip/hip_runtime.h>
#include <hip/hip_bf16.h>

#define D_DIM 768
#define K_CL  512
#define BM    128
#define BK    32
#define NSTEP (D_DIM / BK)   // 24
#define LDS_STRIDE 40        // BK + 8 pad: 80B row pitch -> conflict-free b128 frag reads

using f32x4 = __attribute__((ext_vector_type(4))) float;
using s16x8 = __attribute__((ext_vector_type(8))) short;
using u16x8 = __attribute__((ext_vector_type(8))) unsigned short;
using u16x4 = __attribute__((ext_vector_type(4))) unsigned short;

static __device__ __forceinline__ unsigned short f2bf(float f) {
    __hip_bfloat16 h = __float2bfloat16(f);   // RTN
    unsigned short u;
    __builtin_memcpy(&u, &h, 2);
    return u;
}

// Pre-pass: C[512][768] fp32 -> bf16 in ws, plus c_sq[512] fp32.
__global__ void prep_centers_kernel(const float* __restrict__ C,
                                    unsigned short* __restrict__ Cb,
                                    float* __restrict__ csq) {
    const int lane = threadIdx.x & 63;
    const int wid  = threadIdx.x >> 6;        // 0..3
    const int row  = blockIdx.x * 4 + wid;    // 0..511
    const float* src = C + (size_t)row * D_DIM;
    unsigned short* dst = Cb + (size_t)row * D_DIM;
    float sq = 0.f;
#pragma unroll
    for (int c = 0; c < 3; ++c) {
        const int d0 = c * 256 + lane * 4;
        f32x4 v = *reinterpret_cast<const f32x4*>(src + d0);
        u16x4 b;
        b[0] = f2bf(v[0]); b[1] = f2bf(v[1]); b[2] = f2bf(v[2]); b[3] = f2bf(v[3]);
        *reinterpret_cast<u16x4*>(dst + d0) = b;
        sq += v[0]*v[0] + v[1]*v[1] + v[2]*v[2] + v[3]*v[3];
    }
#pragma unroll
    for (int m = 1; m < 64; m <<= 1) sq += __shfl_xor(sq, m, 64);
    if (lane == 0) csq[row] = sq;
}

// Main: per block, 128 rows x all 512 clusters. GEMM (bf16 MFMA) + fused
// Student-t epilogue + deterministic row normalization.
__global__ __launch_bounds__(1024, 4) void dec_main_kernel(
    const float* __restrict__ X,
    const unsigned short* __restrict__ Cb,
    const float* __restrict__ csq,
    const float* __restrict__ alpha_ptr,
    float* __restrict__ out)
{
    __shared__ unsigned short Al[2][BM * LDS_STRIDE];     // 2*10240 B
    __shared__ unsigned short Bl[2][K_CL * LDS_STRIDE];   // 2*40960 B
    __shared__ float part[8][BM];                         // 4 KB
    __shared__ float xsql[BM];
    __shared__ float invl[BM];

    const int tid  = threadIdx.x;
    const int lane = tid & 63;
    const int wid  = tid >> 6;        // 0..15
    const int wm   = wid >> 3;        // 0..1  (wave row)
    const int wn   = wid & 7;         // 0..7  (wave col)
    const int m0   = blockIdx.x * BM;

    // A staging: 8 threads per row, float4 each; same row every K-step
    const int arow = tid >> 3;                 // 0..127
    const int acol = (tid & 7) * 4;            // 0..28
    const float* aptr = X + (size_t)(m0 + arow) * D_DIM + acol;

    // B staging: bf16x8 chunks, 4 threads per row, 2 rows per thread
    const int brow0 = tid >> 2;                // 0..255
    const int bch   = (tid & 3) * 8;           // 0,8,16,24
    const int brow1 = brow0 + 256;             // 256..511
    const unsigned short* bptr0 = Cb + (size_t)brow0 * D_DIM + bch;
    const unsigned short* bptr1 = Cb + (size_t)brow1 * D_DIM + bch;

    const int a_woff  = arow * LDS_STRIDE + acol;
    const int b_woff0 = brow0 * LDS_STRIDE + bch;
    const int b_woff1 = brow1 * LDS_STRIDE + bch;

    // fragment read coords (16x16x32: lane holds [lane&15][(lane>>4)*8 + j])
    const int fr = lane & 15;
    const int fg = lane >> 4;
    const int a_roff = (wm * 64 + fr) * LDS_STRIDE + fg * 8;
    const int b_roff = (wn * 64 + fr) * LDS_STRIDE + fg * 8;

    f32x4 acc[4][4] = {};

    // prologue: g2r tile 0
    f32x4 areg = *reinterpret_cast<const f32x4*>(aptr);
    u16x8 breg0 = *reinterpret_cast<const u16x8*>(bptr0);
    u16x8 breg1 = *reinterpret_cast<const u16x8*>(bptr1);
    float sqp = 0.f;

    for (int t = 0; t < NSTEP; ++t) {
        const int buf = t & 1;
        // reg -> LDS (convert A to bf16, accumulate ||x||^2 partial)
        u16x4 ab;
        ab[0] = f2bf(areg[0]); ab[1] = f2bf(areg[1]);
        ab[2] = f2bf(areg[2]); ab[3] = f2bf(areg[3]);
        sqp += areg[0]*areg[0] + areg[1]*areg[1] + areg[2]*areg[2] + areg[3]*areg[3];
        *reinterpret_cast<u16x4*>(&Al[buf][a_woff]) = ab;
        *reinterpret_cast<u16x8*>(&Bl[buf][b_woff0]) = breg0;
        *reinterpret_cast<u16x8*>(&Bl[buf][b_woff1]) = breg1;
        __syncthreads();
        // g2r next tile (overlaps with compute below)
        if (t + 1 < NSTEP) {
            const int d = (t + 1) * BK;
            areg  = *reinterpret_cast<const f32x4*>(aptr + d);
            breg0 = *reinterpret_cast<const u16x8*>(bptr0 + d);
            breg1 = *reinterpret_cast<const u16x8*>(bptr1 + d);
        }
        // compute on buf (double-buffered: next iter writes buf^1, no 2nd barrier)
        s16x8 afr[4];
#pragma unroll
        for (int mf = 0; mf < 4; ++mf)
            afr[mf] = *reinterpret_cast<const s16x8*>(&Al[buf][a_roff + mf * 16 * LDS_STRIDE]);
#pragma unroll
        for (int nf = 0; nf < 4; ++nf) {
            s16x8 bfr = *reinterpret_cast<const s16x8*>(&Bl[buf][b_roff + nf * 16 * LDS_STRIDE]);
#pragma unroll
            for (int mf = 0; mf < 4; ++mf)
                acc[mf][nf] = __builtin_amdgcn_mfma_f32_16x16x32_bf16(
                    afr[mf], bfr, acc[mf][nf], 0, 0, 0);
        }
    }

    // ||x||^2: reduce 8 partials per row (deterministic shuffle tree)
    sqp += __shfl_xor(sqp, 1, 64);
    sqp += __shfl_xor(sqp, 2, 64);
    sqp += __shfl_xor(sqp, 4, 64);
    if ((tid & 7) == 0) xsql[arow] = sqp;
    __syncthreads();

    const float alpha     = alpha_ptr[0];
    const float inv_alpha = 1.0f / alpha;
    const float power     = 0.5f * (alpha + 1.0f);
    const bool  p1        = (power == 1.0f);

    float csqr[4];
#pragma unroll
    for (int nf = 0; nf < 4; ++nf)
        csqr[nf] = csq[wn * 64 + nf * 16 + fr];

    // numerator + per-row partial sums (16-lane butterfly within col group)
#pragma unroll
    for (int mf = 0; mf < 4; ++mf) {
#pragma unroll
        for (int j = 0; j < 4; ++j) {
            const int rloc = wm * 64 + mf * 16 + fg * 4 + j;
            const float xs = xsql[rloc];
            float rp = 0.f;
#pragma unroll
            for (int nf = 0; nf < 4; ++nf) {
                float d2 = xs + csqr[nf] - 2.0f * acc[mf][nf][j];
                d2 = fmaxf(d2, 0.0f);
                const float base = 1.0f + d2 * inv_alpha;
                const float nm = p1 ? (1.0f / base)
                                    : exp2f(-power * log2f(base));
                acc[mf][nf][j] = nm;
                rp += nm;
            }
#pragma unroll
            for (int m = 1; m < 16; m <<= 1) rp += __shfl_xor(rp, m, 64);
            if (fr == 0) part[wn][rloc] = rp;
        }
    }
    __syncthreads();
    if (tid < BM) {
        float s = 0.f;
#pragma unroll
        for (int w = 0; w < 8; ++w) s += part[w][tid];
        invl[tid] = 1.0f / s;
    }
    __syncthreads();

    // scaled store
#pragma unroll
    for (int mf = 0; mf < 4; ++mf) {
#pragma unroll
        for (int j = 0; j < 4; ++j) {
            const int rloc = wm * 64 + mf * 16 + fg * 4 + j;
            const float iv = invl[rloc];
            float* orow = out + (size_t)(m0 + rloc) * K_CL + wn * 64 + fr;
#pragma unroll
            for (int nf = 0; nf < 4; ++nf)
                orow[nf * 16] = acc[mf][nf][j] * iv;
        }
    }
}

extern "C" void kernel_launch(void* const* d_in, const int* in_sizes, int n_in,
                              void* d_out, int out_size, void* d_ws, size_t ws_size,
                              hipStream_t stream) {
    const float* X     = (const float*)d_in[0];
    const float* C     = (const float*)d_in[1];
    const float* alpha = (const float*)d_in[2];
    float* out = (float*)d_out;
    const int N = in_sizes[0] / D_DIM;   // 65536

    unsigned short* Cb = (unsigned short*)d_ws;
    float* csq = (float*)((char*)d_ws + (size_t)K_CL * D_DIM * sizeof(unsigned short));

    prep_centers_kernel<<<K_CL / 4, 256, 0, stream>>>(C, Cb, csq);
    dec_main_kernel<<<N / BM, 1024, 0, stream>>>(X, Cb, csq, alpha, out);
}

// Round 2
// 114.725 us; speedup vs baseline: 1.3145x; 1.3145x over previous
//
#include <hip/hip_runtime.h>
#include <hip/hip_bf16.h>

#define D_DIM 768
#define K_CL  512
#define BM    64
#define BK    32
#define NSTEP 24          // 768 / 32

using f32x4 = __attribute__((ext_vector_type(4))) float;
using s16x8 = __attribute__((ext_vector_type(8))) short;
using u16x8 = __attribute__((ext_vector_type(8))) unsigned short;
using u16x4 = __attribute__((ext_vector_type(4))) unsigned short;
typedef unsigned int u32;

static __device__ __forceinline__ unsigned short f2bf(float f) {
    __hip_bfloat16 h = __float2bfloat16(f);   // RTN
    unsigned short u;
    __builtin_memcpy(&u, &h, 2);
    return u;
}

static __device__ __forceinline__ void gload_lds16(const void* g, void* l) {
    __builtin_amdgcn_global_load_lds(
        (const __attribute__((address_space(1))) u32*)g,
        (__attribute__((address_space(3))) u32*)l, 16, 0, 0);
}

// Prepass: C[512][768] fp32 -> bf16 workspace in "LDS image" layout:
// granule (16B = 8 bf16) index  g = t*2048 + r*4 + (s ^ ((r>>1)&3))
// holds C[r][t*32 + s*8 .. +8).  Also c_sq[512].
// One block per row r; 64 threads.
__global__ void prep_centers_kernel(const float* __restrict__ C,
                                    unsigned short* __restrict__ Cbws,
                                    float* __restrict__ csq) {
    const int r = blockIdx.x;          // 0..511
    const int l = threadIdx.x;         // 0..63
    const float* src = C + (size_t)r * D_DIM;
    float sq = 0.f;
#pragma unroll
    for (int jj = 0; jj < 2; ++jj) {
        const int j = l + jj * 64;     // 0..127, only 0..95 valid
        if (j < 96) {
            const int t = j >> 2, s = j & 3;
            const int k0 = t * 32 + s * 8;
            f32x4 v0 = *reinterpret_cast<const f32x4*>(src + k0);
            f32x4 v1 = *reinterpret_cast<const f32x4*>(src + k0 + 4);
            u16x8 b;
            b[0] = f2bf(v0[0]); b[1] = f2bf(v0[1]); b[2] = f2bf(v0[2]); b[3] = f2bf(v0[3]);
            b[4] = f2bf(v1[0]); b[5] = f2bf(v1[1]); b[6] = f2bf(v1[2]); b[7] = f2bf(v1[3]);
            sq += v0[0]*v0[0] + v0[1]*v0[1] + v0[2]*v0[2] + v0[3]*v0[3]
                + v1[0]*v1[0] + v1[1]*v1[1] + v1[2]*v1[2] + v1[3]*v1[3];
            const int g = t * 2048 + r * 4 + (s ^ ((r >> 1) & 3));
            *reinterpret_cast<u16x8*>(Cbws + (size_t)g * 8) = b;
        }
    }
#pragma unroll
    for (int m = 1; m < 64; m <<= 1) sq += __shfl_xor(sq, m, 64);
    if (l == 0) csq[r] = sq;
}

// Main: per block 64 rows x all 512 clusters. 8 waves, wave tile 64x64.
// B staged via global_load_lds (pre-swizzled source -> linear DMA, swizzled reads).
// A reg-staged fp32->bf16 with matching XOR swizzle. 2 blocks/CU.
__global__ __launch_bounds__(512, 4) void dec_main_kernel(
    const float* __restrict__ X,
    const unsigned short* __restrict__ Cbws,
    const float* __restrict__ csq,
    const float* __restrict__ alpha_ptr,
    float* __restrict__ out)
{
    __shared__ unsigned short Al[2][BM * BK];      // 2 * 4 KB
    __shared__ unsigned short Bl[2][K_CL * BK];    // 2 * 32 KB
    __shared__ float part[8][BM];                  // 2 KB
    __shared__ float xsql[BM];
    __shared__ float invl[BM];

    const int tid  = threadIdx.x;      // 0..511
    const int lane = tid & 63;
    const int wn   = tid >> 6;         // 0..7 (wave = one 64-col cluster stripe)
    const int m0   = blockIdx.x * BM;

    // ---- A staging: 8 threads per row, float4 each ----
    const int arow  = tid >> 3;        // 0..63
    const int acol8 = tid & 7;         // 8B sub-chunk within 64B row
    const float* aptr = X + (size_t)(m0 + arow) * D_DIM + acol8 * 4;
    const int awbyte = arow * 64
                     + ((((acol8 >> 1) ^ ((arow >> 1) & 3))) << 4)
                     + (acol8 & 1) * 8;

    // ---- fragment read offsets (XOR-swizzled, 2-way bank = free) ----
    const int fr = lane & 15;
    const int fg = lane >> 4;          // 0..3, k-slot
    int aoff[4], boff[4];
#pragma unroll
    for (int mf = 0; mf < 4; ++mf) {
        const int r = mf * 16 + fr;
        aoff[mf] = r * 64 + ((fg ^ ((r >> 1) & 3)) << 4);
    }
#pragma unroll
    for (int nf = 0; nf < 4; ++nf) {
        const int r = wn * 64 + nf * 16 + fr;
        boff[nf] = r * 64 + ((fg ^ ((r >> 1) & 3)) << 4);
    }

    f32x4 acc[4][4] = {};

    // ---- prologue: issue B(0) DMA, load A(0) ----
    {
        const unsigned short* bs = Cbws + (size_t)tid * 8;
#pragma unroll
        for (int q = 0; q < 4; ++q)
            gload_lds16(bs + (size_t)q * 512 * 8,
                        (char*)&Bl[0][0] + ((size_t)q * 512 + tid) * 16);
    }
    f32x4 areg = *reinterpret_cast<const f32x4*>(aptr);
    float sqp = 0.f;

    for (int t = 0; t < NSTEP; ++t) {
        const int buf = t & 1;
        // convert + write A tile (to buf), accumulate ||x||^2 partial
        u16x4 ab;
        ab[0] = f2bf(areg[0]); ab[1] = f2bf(areg[1]);
        ab[2] = f2bf(areg[2]); ab[3] = f2bf(areg[3]);
        sqp += areg[0]*areg[0] + areg[1]*areg[1] + areg[2]*areg[2] + areg[3]*areg[3];
        *reinterpret_cast<u16x4*>((char*)&Al[buf][0] + awbyte) = ab;
        __syncthreads();   // drains B(t) DMA (vmcnt), publishes A(t)
        if (t + 1 < NSTEP) {
            const unsigned short* bs = Cbws + (size_t)(t + 1) * 2048 * 8 + (size_t)tid * 8;
#pragma unroll
            for (int q = 0; q < 4; ++q)
                gload_lds16(bs + (size_t)q * 512 * 8,
                            (char*)&Bl[buf ^ 1][0] + ((size_t)q * 512 + tid) * 16);
            areg = *reinterpret_cast<const f32x4*>(aptr + (t + 1) * BK);
        }
        // compute on buf
        s16x8 afr[4];
#pragma unroll
        for (int mf = 0; mf < 4; ++mf)
            afr[mf] = *reinterpret_cast<const s16x8*>((const char*)&Al[buf][0] + aoff[mf]);
#pragma unroll
        for (int nf = 0; nf < 4; ++nf) {
            s16x8 bfr = *reinterpret_cast<const s16x8*>((const char*)&Bl[buf][0] + boff[nf]);
#pragma unroll
            for (int mf = 0; mf < 4; ++mf)
                acc[mf][nf] = __builtin_amdgcn_mfma_f32_16x16x32_bf16(
                    afr[mf], bfr, acc[mf][nf], 0, 0, 0);
        }
    }

    // ---- ||x||^2 per row: reduce 8 staging threads ----
    sqp += __shfl_xor(sqp, 1, 64);
    sqp += __shfl_xor(sqp, 2, 64);
    sqp += __shfl_xor(sqp, 4, 64);
    if ((tid & 7) == 0) xsql[arow] = sqp;
    __syncthreads();

    const float alpha     = alpha_ptr[0];
    const float inv_alpha = 1.0f / alpha;
    const float power     = 0.5f * (alpha + 1.0f);
    const bool  p1        = (power == 1.0f);

    float csqr[4];
#pragma unroll
    for (int nf = 0; nf < 4; ++nf)
        csqr[nf] = csq[wn * 64 + nf * 16 + fr];

    // numerator + per-row partial sums (16-lane butterfly in col group)
#pragma unroll
    for (int mf = 0; mf < 4; ++mf) {
#pragma unroll
        for (int j = 0; j < 4; ++j) {
            const int rloc = mf * 16 + fg * 4 + j;
            const float xs = xsql[rloc];
            float rp = 0.f;
#pragma unroll
            for (int nf = 0; nf < 4; ++nf) {
                float d2 = xs + csqr[nf] - 2.0f * acc[mf][nf][j];
                d2 = fmaxf(d2, 0.0f);
                const float base = 1.0f + d2 * inv_alpha;
                const float nm = p1 ? (1.0f / base)
                                    : exp2f(-power * log2f(base));
                acc[mf][nf][j] = nm;
                rp += nm;
            }
#pragma unroll
            for (int m = 1; m < 16; m <<= 1) rp += __shfl_xor(rp, m, 64);
            if (fr == 0) part[wn][rloc] = rp;
        }
    }
    __syncthreads();
    if (tid < BM) {
        float s = 0.f;
#pragma unroll
        for (int w = 0; w < 8; ++w) s += part[w][tid];
        invl[tid] = 1.0f / s;
    }
    __syncthreads();

    // scaled store (16 consecutive lanes -> 64B contiguous segments)
#pragma unroll
    for (int mf = 0; mf < 4; ++mf) {
#pragma unroll
        for (int j = 0; j < 4; ++j) {
            const int rloc = mf * 16 + fg * 4 + j;
            const float iv = invl[rloc];
            float* orow = out + (size_t)(m0 + rloc) * K_CL + wn * 64 + fr;
#pragma unroll
            for (int nf = 0; nf < 4; ++nf)
                orow[nf * 16] = acc[mf][nf][j] * iv;
        }
    }
}

extern "C" void kernel_launch(void* const* d_in, const int* in_sizes, int n_in,
                              void* d_out, int out_size, void* d_ws, size_t ws_size,
                              hipStream_t stream) {
    const float* X     = (const float*)d_in[0];
    const float* C     = (const float*)d_in[1];
    const float* alpha = (const float*)d_in[2];
    float* out = (float*)d_out;
    const int N = in_sizes[0] / D_DIM;   // 65536

    unsigned short* Cbws = (unsigned short*)d_ws;
    float* csq = (float*)((char*)d_ws + (size_t)K_CL * D_DIM * sizeof(unsigned short));

    prep_centers_kernel<<<K_CL, 64, 0, stream>>>(C, Cbws, csq);
    dec_main_kernel<<<N / BM, 512, 0, stream>>>(X, Cbws, csq, alpha, out);
}

// Round 3
// 114.163 us; speedup vs baseline: 1.3210x; 1.0049x over previous
//
#include <hip/hip_runtime.h>
#include <hip/hip_bf16.h>

#define D_DIM 768
#define K_CL  512
#define BM    64
#define BK    32
#define NSTEP 24          // 768 / 32

using f32x4 = __attribute__((ext_vector_type(4))) float;
using s16x8 = __attribute__((ext_vector_type(8))) short;
using u16x8 = __attribute__((ext_vector_type(8))) unsigned short;
using u16x4 = __attribute__((ext_vector_type(4))) unsigned short;
typedef unsigned int u32;

static __device__ __forceinline__ unsigned short f2bf(float f) {
    __hip_bfloat16 h = __float2bfloat16(f);   // RTN
    unsigned short u;
    __builtin_memcpy(&u, &h, 2);
    return u;
}

static __device__ __forceinline__ void gload_lds16(const void* g, void* l) {
    __builtin_amdgcn_global_load_lds(
        (const __attribute__((address_space(1))) u32*)g,
        (__attribute__((address_space(3))) u32*)l, 16, 0, 0);
}

// Prepass: C[512][768] fp32 -> bf16 workspace in "LDS image" layout:
// granule (16B = 8 bf16) index  g = t*2048 + r*4 + (s ^ ((r>>1)&3))
// holds C[r][t*32 + s*8 .. +8).  Also c_sq[512].
__global__ void prep_centers_kernel(const float* __restrict__ C,
                                    unsigned short* __restrict__ Cbws,
                                    float* __restrict__ csq) {
    const int r = blockIdx.x;          // 0..511
    const int l = threadIdx.x;         // 0..63
    const float* src = C + (size_t)r * D_DIM;
    float sq = 0.f;
#pragma unroll
    for (int jj = 0; jj < 2; ++jj) {
        const int j = l + jj * 64;     // 0..127, only 0..95 valid
        if (j < 96) {
            const int t = j >> 2, s = j & 3;
            const int k0 = t * 32 + s * 8;
            f32x4 v0 = *reinterpret_cast<const f32x4*>(src + k0);
            f32x4 v1 = *reinterpret_cast<const f32x4*>(src + k0 + 4);
            u16x8 b;
            b[0] = f2bf(v0[0]); b[1] = f2bf(v0[1]); b[2] = f2bf(v0[2]); b[3] = f2bf(v0[3]);
            b[4] = f2bf(v1[0]); b[5] = f2bf(v1[1]); b[6] = f2bf(v1[2]); b[7] = f2bf(v1[3]);
            sq += v0[0]*v0[0] + v0[1]*v0[1] + v0[2]*v0[2] + v0[3]*v0[3]
                + v1[0]*v1[0] + v1[1]*v1[1] + v1[2]*v1[2] + v1[3]*v1[3];
            const int g = t * 2048 + r * 4 + (s ^ ((r >> 1) & 3));
            *reinterpret_cast<u16x8*>(Cbws + (size_t)g * 8) = b;
        }
    }
#pragma unroll
    for (int m = 1; m < 64; m <<= 1) sq += __shfl_xor(sq, m, 64);
    if (l == 0) csq[r] = sq;
}

// Main: 64 rows x 512 clusters per block, 8 waves (wave tile 64x64).
// B via global_load_lds double-buffer with COUNTED vmcnt across raw barriers
// (T3/T4): DMA(t+1) has the full K-step to complete, never drained to 0.
__global__ __launch_bounds__(512, 4) void dec_main_kernel(
    const float* __restrict__ X,
    const unsigned short* __restrict__ Cbws,
    const float* __restrict__ csq,
    const float* __restrict__ alpha_ptr,
    float* __restrict__ out)
{
    __shared__ unsigned short Al[2][BM * BK];      // 2 * 4 KB
    __shared__ unsigned short Bl[2][K_CL * BK];    // 2 * 32 KB
    __shared__ float part[8][BM];                  // 2 KB
    __shared__ float xsql[BM];
    __shared__ float invl[BM];

    const int tid  = threadIdx.x;      // 0..511
    const int lane = tid & 63;
    const int wn   = tid >> 6;         // 0..7
    const int m0   = blockIdx.x * BM;

    // A staging: 8 threads per row, float4 each
    const int arow  = tid >> 3;
    const int acol8 = tid & 7;
    const float* aptr = X + (size_t)(m0 + arow) * D_DIM + acol8 * 4;
    const int awbyte = arow * 64
                     + ((((acol8 >> 1) ^ ((arow >> 1) & 3))) << 4)
                     + (acol8 & 1) * 8;

    // fragment read offsets (XOR-swizzled)
    const int fr = lane & 15;
    const int fg = lane >> 4;
    int aoff[4], boff[4];
#pragma unroll
    for (int mf = 0; mf < 4; ++mf) {
        const int r = mf * 16 + fr;
        aoff[mf] = r * 64 + ((fg ^ ((r >> 1) & 3)) << 4);
    }
#pragma unroll
    for (int nf = 0; nf < 4; ++nf) {
        const int r = wn * 64 + nf * 16 + fr;
        boff[nf] = r * 64 + ((fg ^ ((r >> 1) & 3)) << 4);
    }

    f32x4 acc[4][4] = {};
    float sqp = 0.f;

    // ---- prologue ----
    f32x4 areg = *reinterpret_cast<const f32x4*>(aptr);         // tile 0
    {
        const unsigned short* bs = Cbws + (size_t)tid * 8;
#pragma unroll
        for (int q = 0; q < 4; ++q)
            gload_lds16(bs + (size_t)q * 512 * 8,
                        (char*)&Bl[0][0] + ((size_t)q * 512 + tid) * 16);
    }
    {   // stage A(0)  (compiler waits vmcnt(4) for areg; B-DMA stays in flight)
        u16x4 ab;
        ab[0] = f2bf(areg[0]); ab[1] = f2bf(areg[1]);
        ab[2] = f2bf(areg[2]); ab[3] = f2bf(areg[3]);
        sqp += areg[0]*areg[0] + areg[1]*areg[1] + areg[2]*areg[2] + areg[3]*areg[3];
        *reinterpret_cast<u16x4*>((char*)&Al[0][0] + awbyte) = ab;
    }
    areg = *reinterpret_cast<const f32x4*>(aptr + BK);          // tile 1
    asm volatile("s_waitcnt vmcnt(1) lgkmcnt(0)" ::: "memory"); // B(0) done
    __builtin_amdgcn_sched_barrier(0);
    __builtin_amdgcn_s_barrier();

#pragma unroll
    for (int t = 0; t < NSTEP; ++t) {
        const int buf = t & 1;
        // 1. issue B-DMA(t+1) -> buf^1 (readers of buf^1 fenced by prev barrier)
        if (t + 1 < NSTEP) {
            const unsigned short* bs = Cbws + (size_t)(t + 1) * 2048 * 8 + (size_t)tid * 8;
#pragma unroll
            for (int q = 0; q < 4; ++q)
                gload_lds16(bs + (size_t)q * 512 * 8,
                            (char*)&Bl[buf ^ 1][0] + ((size_t)q * 512 + tid) * 16);
        }
        // 2. compute(t) on buf
        {
            s16x8 afr[4];
#pragma unroll
            for (int mf = 0; mf < 4; ++mf)
                afr[mf] = *reinterpret_cast<const s16x8*>((const char*)&Al[buf][0] + aoff[mf]);
            __builtin_amdgcn_s_setprio(1);
#pragma unroll
            for (int nf = 0; nf < 4; ++nf) {
                s16x8 bfr = *reinterpret_cast<const s16x8*>((const char*)&Bl[buf][0] + boff[nf]);
#pragma unroll
                for (int mf = 0; mf < 4; ++mf)
                    acc[mf][nf] = __builtin_amdgcn_mfma_f32_16x16x32_bf16(
                        afr[mf], bfr, acc[mf][nf], 0, 0, 0);
            }
            __builtin_amdgcn_s_setprio(0);
        }
        // 3. stage A(t+1), prefetch A(t+2), counted wait + barrier
        if (t + 1 < NSTEP) {
            u16x4 ab;
            ab[0] = f2bf(areg[0]); ab[1] = f2bf(areg[1]);
            ab[2] = f2bf(areg[2]); ab[3] = f2bf(areg[3]);
            sqp += areg[0]*areg[0] + areg[1]*areg[1] + areg[2]*areg[2] + areg[3]*areg[3];
            *reinterpret_cast<u16x4*>((char*)&Al[buf ^ 1][0] + awbyte) = ab;
            if (t + 2 < NSTEP) {
                areg = *reinterpret_cast<const f32x4*>(aptr + (t + 2) * BK);
                asm volatile("s_waitcnt vmcnt(1) lgkmcnt(0)" ::: "memory"); // B(t+1) done, A-load in flight
            } else {
                asm volatile("s_waitcnt vmcnt(0) lgkmcnt(0)" ::: "memory");
            }
            __builtin_amdgcn_sched_barrier(0);
            __builtin_amdgcn_s_barrier();
        }
    }

    // ---- ||x||^2 per row ----
    sqp += __shfl_xor(sqp, 1, 64);
    sqp += __shfl_xor(sqp, 2, 64);
    sqp += __shfl_xor(sqp, 4, 64);
    if ((tid & 7) == 0) xsql[arow] = sqp;
    __syncthreads();

    const float alpha     = alpha_ptr[0];
    const float inv_alpha = 1.0f / alpha;
    const float power     = 0.5f * (alpha + 1.0f);
    const bool  p1        = (power == 1.0f);

    float csqr[4];
#pragma unroll
    for (int nf = 0; nf < 4; ++nf)
        csqr[nf] = csq[wn * 64 + nf * 16 + fr];

#pragma unroll
    for (int mf = 0; mf < 4; ++mf) {
#pragma unroll
        for (int j = 0; j < 4; ++j) {
            const int rloc = mf * 16 + fg * 4 + j;
            const float xs = xsql[rloc];
            float rp = 0.f;
#pragma unroll
            for (int nf = 0; nf < 4; ++nf) {
                float d2 = xs + csqr[nf] - 2.0f * acc[mf][nf][j];
                d2 = fmaxf(d2, 0.0f);
                const float base = 1.0f + d2 * inv_alpha;
                const float nm = p1 ? (1.0f / base)
                                    : exp2f(-power * log2f(base));
                acc[mf][nf][j] = nm;
                rp += nm;
            }
#pragma unroll
            for (int m = 1; m < 16; m <<= 1) rp += __shfl_xor(rp, m, 64);
            if (fr == 0) part[wn][rloc] = rp;
        }
    }
    __syncthreads();
    if (tid < BM) {
        float s = 0.f;
#pragma unroll
        for (int w = 0; w < 8; ++w) s += part[w][tid];
        invl[tid] = 1.0f / s;
    }
    __syncthreads();

#pragma unroll
    for (int mf = 0; mf < 4; ++mf) {
#pragma unroll
        for (int j = 0; j < 4; ++j) {
            const int rloc = mf * 16 + fg * 4 + j;
            const float iv = invl[rloc];
            float* orow = out + (size_t)(m0 + rloc) * K_CL + wn * 64 + fr;
#pragma unroll
            for (int nf = 0; nf < 4; ++nf)
                orow[nf * 16] = acc[mf][nf][j] * iv;
        }
    }
}

extern "C" void kernel_launch(void* const* d_in, const int* in_sizes, int n_in,
                              void* d_out, int out_size, void* d_ws, size_t ws_size,
                              hipStream_t stream) {
    const float* X     = (const float*)d_in[0];
    const float* C     = (const float*)d_in[1];
    const float* alpha = (const float*)d_in[2];
    float* out = (float*)d_out;
    const int N = in_sizes[0] / D_DIM;   // 65536

    unsigned short* Cbws = (unsigned short*)d_ws;
    float* csq = (float*)((char*)d_ws + (size_t)K_CL * D_DIM * sizeof(unsigned short));

    prep_centers_kernel<<<K_CL, 64, 0, stream>>>(C, Cbws, csq);
    dec_main_kernel<<<N / BM, 512, 0, stream>>>(X, Cbws, csq, alpha, out);
}